// Round 4
// baseline (177.603 us; speedup 1.0000x reference)
//
#include <hip/hip_runtime.h>

typedef short s16x8 __attribute__((ext_vector_type(8)));
typedef float f32x4 __attribute__((ext_vector_type(4)));

__device__ inline unsigned short bf16_rn(float f) {
  unsigned int u = __float_as_uint(f);
  return (unsigned short)((u + 0x7FFFu + ((u >> 16) & 1u)) >> 16);
}
__device__ inline float bf16f(unsigned short h) {
  return __uint_as_float(((unsigned int)h) << 16);
}

// async global->LDS DMA, 16 B per lane; LDS dest = wave-uniform base + lane*16
typedef __attribute__((address_space(3))) unsigned int lds_u32_t;
typedef __attribute__((address_space(1))) const unsigned int g_u32_t;
__device__ __forceinline__ void gload_lds16(const void* g, void* l) {
  __builtin_amdgcn_global_load_lds((g_u32_t*)g, (lds_u32_t*)l, 16, 0, 0);
}

// ---------------------------------------------------------------------------
// Kernel 1: codebook -> superblocked XOR-swizzled hi/lo bf16 image + norms.
// 16 superblocks of 32 KB; superblock s = [codes s*32..s*32+31 (half A) |
// codes 512+s*32.. (half B)], each half = [hi 32x128 | lo 32x128] ushorts.
// Row r stores 8-dim chunk c at slot c ^ (r & 15) (conflict-free ds_read).
// ---------------------------------------------------------------------------
__global__ __launch_bounds__(64) void vq_convert_cb(const float* __restrict__ cb,
                                                    unsigned short* __restrict__ cbimg,
                                                    float* __restrict__ cbn) {
  int k = blockIdx.x * 64 + threadIdx.x;  // 0..1023
  int half = k >> 9;                      // codebook half
  int s = (k >> 5) & 15;                  // superblock
  int r = k & 31, sm = r & 15;
  const float* row = cb + (size_t)k * 128;
  unsigned short* base = cbimg + (size_t)s * 16384 + half * 8192 + r * 128;
  float nrm = 0.f;
#pragma unroll
  for (int c = 0; c < 16; ++c) {
    float4 a = *(const float4*)(row + c * 8);
    float4 b = *(const float4*)(row + c * 8 + 4);
    float v[8] = {a.x, a.y, a.z, a.w, b.x, b.y, b.z, b.w};
    unsigned int hw[4], lw[4];
#pragma unroll
    for (int i = 0; i < 4; ++i) {
      unsigned short h0 = bf16_rn(v[2 * i]), h1 = bf16_rn(v[2 * i + 1]);
      float r0 = v[2 * i] - bf16f(h0), r1 = v[2 * i + 1] - bf16f(h1);
      unsigned short l0 = bf16_rn(r0), l1 = bf16_rn(r1);
      hw[i] = (unsigned)h0 | ((unsigned)h1 << 16);
      lw[i] = (unsigned)l0 | ((unsigned)l1 << 16);
      nrm += v[2 * i] * v[2 * i] + v[2 * i + 1] * v[2 * i + 1];
    }
    int cs = c ^ sm;
    *(uint4*)(base + cs * 8) = make_uint4(hw[0], hw[1], hw[2], hw[3]);
    *(uint4*)(base + cs * 8 + 4096) = make_uint4(lw[0], lw[1], lw[2], lw[3]);
  }
  cbn[k] = nrm;
}

// ---------------------------------------------------------------------------
// Kernel 2: fused main, split-N. 512 blocks x 512 thr (8 waves, (512,4)).
// Waves 0-3 own 32 tokens each over codes 0-511; waves 4-7 own the SAME
// tokens over codes 512-1023. 2x B-reuse per LDS read (0.042 B/MAC) halves
// the LDS-port load (the R3 critical pipe) below the MFMA floor. 16 super-
// block phases through dbuf LDS (64 KB) with top-of-phase async prefetch;
// 3-pass split-bf16 MFMA + setprio; min/max exact top-2 per half; epilogue
// rescores the 4-candidate union exactly in fp32; block-local loss.
// ---------------------------------------------------------------------------
__global__ __launch_bounds__(512, 4) void vq_main(
    const float* __restrict__ xg, const float* __restrict__ cb,
    const unsigned short* __restrict__ cbimg, const float* __restrict__ cbn,
    float* __restrict__ xq, float* __restrict__ loss) {
  __shared__ __attribute__((aligned(16))) unsigned short sB[2][16384];  // 64 KB
  __shared__ float sNorm[1024];
  __shared__ int sKK[256];  // [half][128 tokens]
  __shared__ float sLoss[8];
  const int tid = threadIdx.x;
  const int wave = tid >> 6, lane = tid & 63;
  const int i0 = lane & 15, q = lane >> 4;
  const int grp = wave >> 2;   // codebook half this wave scans
  const int wv = wave & 3;     // token-group id
  const int tokW = blockIdx.x * 128 + wv * 32;

  // ---- stage codebook norms into LDS (4 KB, 512 thr x float2) ----
  *(float2*)&sNorm[tid * 2] = *(const float2*)(cbn + tid * 2);

  // ---- load own 32 tokens, split fp32 -> bf16 hi + bf16 lo in-register ----
  s16x8 ahi[2][4], alo[2][4];
#pragma unroll
  for (int r = 0; r < 2; ++r)
#pragma unroll
    for (int kf = 0; kf < 4; ++kf) {
      const float* p = xg + (size_t)(tokW + r * 16 + i0) * 128 + kf * 32 + q * 8;
      float4 a = *(const float4*)p, b = *(const float4*)(p + 4);
      float v[8] = {a.x, a.y, a.z, a.w, b.x, b.y, b.z, b.w};
      s16x8 h, l;
#pragma unroll
      for (int j = 0; j < 8; ++j) {
        unsigned short hh = bf16_rn(v[j]);
        float rr = v[j] - bf16f(hh);
        h[j] = (short)hh;
        l[j] = (short)bf16_rn(rr);
      }
      ahi[r][kf] = h;
      alo[r][kf] = l;
    }

  int boff[4][2];  // LDS ushort offsets into own half (XOR de-swizzle)
#pragma unroll
  for (int ks = 0; ks < 4; ++ks)
#pragma unroll
    for (int c = 0; c < 2; ++c)
      boff[ks][c] = grp * 8192 + (c * 16 + i0) * 128 + (((ks * 4 + q) ^ i0) * 8);

  // ---- async stage superblock 0 (4 x 1KB slices per wave, 8 waves = 32 KB) ----
  const char* gbase = (const char*)cbimg;
  const int so = wave * 4096 + lane * 16;  // per-lane global offset in superblock
  const int su = wave * 4096;              // wave-uniform LDS offset
  {
    const char* g = gbase + so;
    char* l = (char*)&sB[0][0] + su;
#pragma unroll
    for (int i = 0; i < 4; ++i) gload_lds16(g + i * 1024, l + i * 1024);
  }

  float d1[2][4], d2[2][4];
  int k1[2][4], k2[2][4];
#pragma unroll
  for (int r = 0; r < 2; ++r)
#pragma unroll
    for (int g = 0; g < 4; ++g) {
      d1[r][g] = 3.4e38f; d2[r][g] = 3.4e38f; k1[r][g] = 0; k2[r][g] = 0;
    }
  __syncthreads();  // drains vmcnt -> superblock 0 resident; sNorm visible

  for (int t = 0; t < 16; ++t) {
    const int cur = t & 1;
    if (t < 15) {  // async prefetch of superblock t+1 (issued BEFORE compute)
      const char* g = gbase + (t + 1) * 32768 + so;
      char* l = (char*)&sB[1 - cur][0] + su;
#pragma unroll
      for (int i = 0; i < 4; ++i) gload_lds16(g + i * 1024, l + i * 1024);
    }
    f32x4 acc[2][2];
#pragma unroll
    for (int r = 0; r < 2; ++r)
#pragma unroll
      for (int c = 0; c < 2; ++c) acc[r][c] = (f32x4){0.f, 0.f, 0.f, 0.f};

#pragma unroll
    for (int ks = 0; ks < 4; ++ks) {
      s16x8 bhi[2], blo[2];
#pragma unroll
      for (int c = 0; c < 2; ++c) {
        bhi[c] = *(const s16x8*)&sB[cur][boff[ks][c]];
        blo[c] = *(const s16x8*)&sB[cur][boff[ks][c] + 4096];
      }
      __builtin_amdgcn_s_setprio(1);
#pragma unroll
      for (int r = 0; r < 2; ++r)
#pragma unroll
        for (int c = 0; c < 2; ++c) {
          acc[r][c] = __builtin_amdgcn_mfma_f32_16x16x32_bf16(ahi[r][ks], bhi[c], acc[r][c], 0, 0, 0);
          acc[r][c] = __builtin_amdgcn_mfma_f32_16x16x32_bf16(ahi[r][ks], blo[c], acc[r][c], 0, 0, 0);
          acc[r][c] = __builtin_amdgcn_mfma_f32_16x16x32_bf16(alo[r][ks], bhi[c], acc[r][c], 0, 0, 0);
        }
      __builtin_amdgcn_s_setprio(0);
    }
    // ---- exact top-2 update (min/max form); strict < keeps first-min ----
#pragma unroll
    for (int c = 0; c < 2; ++c) {
      int kc = grp * 512 + t * 32 + c * 16 + i0;
      float cn = sNorm[kc];
#pragma unroll
      for (int r = 0; r < 2; ++r)
#pragma unroll
        for (int g = 0; g < 4; ++g) {
          float dd = fmaf(-2.f, acc[r][c][g], cn);
          bool w = dd < d1[r][g];
          float ld = fmaxf(dd, d1[r][g]);  // loser of {dd, d1}
          int lk = w ? k1[r][g] : kc;      // loser's key (tie -> larger kc)
          d1[r][g] = fminf(dd, d1[r][g]);
          k1[r][g] = w ? kc : k1[r][g];
          bool w2 = ld < d2[r][g];
          d2[r][g] = fminf(ld, d2[r][g]);
          k2[r][g] = w2 ? lk : k2[r][g];
        }
    }
    __syncthreads();  // waves done reading cur; prefetch into 1-cur drained
  }

  // ---- butterfly merge of top-2 across the 16 i0-lanes (lex d,k) ----
#pragma unroll
  for (int off = 1; off < 16; off <<= 1) {
#pragma unroll
    for (int r = 0; r < 2; ++r)
#pragma unroll
      for (int g = 0; g < 4; ++g) {
        float od1 = __shfl_xor(d1[r][g], off);
        int ok1 = __shfl_xor(k1[r][g], off);
        float od2 = __shfl_xor(d2[r][g], off);
        int ok2 = __shfl_xor(k2[r][g], off);
        bool t1 = (od1 < d1[r][g]) || (od1 == d1[r][g] && ok1 < k1[r][g]);
        float w1d = t1 ? od1 : d1[r][g];
        int w1k = t1 ? ok1 : k1[r][g];
        float l1d = t1 ? d1[r][g] : od1;  // loser of the firsts
        int l1k = t1 ? k1[r][g] : ok1;
        float c2d = t1 ? od2 : d2[r][g];  // winner's own second
        int c2k = t1 ? ok2 : k2[r][g];
        bool t2 = (l1d < c2d) || (l1d == c2d && l1k < c2k);
        d1[r][g] = w1d; k1[r][g] = w1k;
        d2[r][g] = t2 ? l1d : c2d;
        k2[r][g] = t2 ? l1k : c2k;
      }
  }

  if (i0 == 0) {
#pragma unroll
    for (int r = 0; r < 2; ++r)
#pragma unroll
      for (int g = 0; g < 4; ++g)
        sKK[grp * 128 + wv * 32 + r * 16 + q * 4 + g] = k1[r][g] | (k2[r][g] << 10);
  }
  __syncthreads();

  // ---- epilogue: exact fp32 rescore of the 4-candidate union (2 per half),
  //      winner re-read (L2-hot) + coalesced xq store; block-local loss ----
  float lacc = 0.f;
  {
    int ltok = wave * 16 + i0;  // each wave rescores 16 of the 128 tokens
    int a = sKK[ltok], b = sKK[128 + ltok];
    int ca = a & 1023, cb2 = (a >> 10) & 1023;
    int cc = b & 1023, cd = (b >> 10) & 1023;
    size_t token = (size_t)blockIdx.x * 128 + ltok;
    float s1 = 0.f, s2 = 0.f, s3 = 0.f, s4 = 0.f;
#pragma unroll
    for (int kf = 0; kf < 4; ++kf) {
      const float* xp = xg + token * 128 + kf * 32 + q * 8;
      float4 xa = *(const float4*)xp, xb = *(const float4*)(xp + 4);
      const float* p1 = cb + (size_t)ca * 128 + kf * 32 + q * 8;
      float4 ua = *(const float4*)p1, ub = *(const float4*)(p1 + 4);
      const float* p2 = cb + (size_t)cb2 * 128 + kf * 32 + q * 8;
      float4 va = *(const float4*)p2, vb = *(const float4*)(p2 + 4);
      const float* p3 = cb + (size_t)cc * 128 + kf * 32 + q * 8;
      float4 wa = *(const float4*)p3, wb = *(const float4*)(p3 + 4);
      const float* p4 = cb + (size_t)cd * 128 + kf * 32 + q * 8;
      float4 ya = *(const float4*)p4, yb = *(const float4*)(p4 + 4);
      float xv[8] = {xa.x, xa.y, xa.z, xa.w, xb.x, xb.y, xb.z, xb.w};
      float e1[8] = {ua.x, ua.y, ua.z, ua.w, ub.x, ub.y, ub.z, ub.w};
      float e2[8] = {va.x, va.y, va.z, va.w, vb.x, vb.y, vb.z, vb.w};
      float e3[8] = {wa.x, wa.y, wa.z, wa.w, wb.x, wb.y, wb.z, wb.w};
      float e4[8] = {ya.x, ya.y, ya.z, ya.w, yb.x, yb.y, yb.z, yb.w};
#pragma unroll
      for (int j = 0; j < 8; ++j) {
        float f1 = xv[j] - e1[j];
        float f2 = xv[j] - e2[j];
        float f3 = xv[j] - e3[j];
        float f4 = xv[j] - e4[j];
        s1 = fmaf(f1, f1, s1);
        s2 = fmaf(f2, f2, s2);
        s3 = fmaf(f3, f3, s3);
        s4 = fmaf(f4, f4, s4);
      }
    }
    s1 += __shfl_xor(s1, 16); s1 += __shfl_xor(s1, 32);
    s2 += __shfl_xor(s2, 16); s2 += __shfl_xor(s2, 32);
    s3 += __shfl_xor(s3, 16); s3 += __shfl_xor(s3, 32);
    s4 += __shfl_xor(s4, 16); s4 += __shfl_xor(s4, 32);
    // pick min distance, ties -> lowest index (matches argmin-first semantics)
    float bs = s1; int bk = ca;
    bool u2 = (s2 < bs) || (s2 == bs && cb2 < bk); bs = u2 ? s2 : bs; bk = u2 ? cb2 : bk;
    bool u3 = (s3 < bs) || (s3 == bs && cc < bk);  bs = u3 ? s3 : bs; bk = u3 ? cc : bk;
    bool u4 = (s4 < bs) || (s4 == bs && cd < bk);  bs = u4 ? s4 : bs; bk = u4 ? cd : bk;
#pragma unroll
    for (int kf = 0; kf < 4; ++kf) {
      const float* pw = cb + (size_t)bk * 128 + kf * 32 + q * 8;
      float4 wa = *(const float4*)pw, wb = *(const float4*)(pw + 4);
      float* op = xq + token * 128 + kf * 32 + q * 8;
      *(float4*)op = wa;
      *(float4*)(op + 4) = wb;
    }
    if (q == 0) lacc += bs;
  }
#pragma unroll
  for (int off = 1; off < 64; off <<= 1) lacc += __shfl_xor(lacc, off);
  if (lane == 0) sLoss[wave] = lacc;
  __syncthreads();
  // block fully owns loss[blockIdx.x] (128 tokens = one (b,s) slice):
  // plain store, no memset, no atomics.
  if (tid == 0) {
    float s = 0.f;
#pragma unroll
    for (int w = 0; w < 8; ++w) s += sLoss[w];
    loss[blockIdx.x] = s * (1.25f / 16384.f);
  }
}

// ---------------------------------------------------------------------------
extern "C" void kernel_launch(void* const* d_in, const int* in_sizes, int n_in,
                              void* d_out, int out_size, void* d_ws, size_t ws_size,
                              hipStream_t stream) {
  const float* x = (const float*)d_in[0];   // [8,64,128,128] fp32
  const float* cb = (const float*)d_in[1];  // [1024,128] fp32
  float* out = (float*)d_out;
  float* xq = out;
  float* loss = out + (size_t)8 * 64 * 128 * 128;  // 512 floats

  // ws: cbimg 512 KB | cbn 4 KB
  unsigned short* cbimg = (unsigned short*)d_ws;
  float* cbn = (float*)(cbimg + (size_t)1024 * 128 * 2);

  vq_convert_cb<<<16, 64, 0, stream>>>(cb, cbimg, cbn);
  vq_main<<<512, 512, 0, stream>>>(x, cb, cbimg, cbn, xq, loss);
}